// Round 4
// baseline (46.961 us; speedup 1.0000x reference)
//
#include <hip/hip_runtime.h>

// Anchor decode (YOLO-style), B=32, A=3, C=14 (7 box/conf + 7 cls), G=152.
// out[b, a2, gy, gx, f] (flattened (B, A*G*G, 15)):
//   f0=im  f1=re  f2=atan(im/re)  f3=sigmoid(conf)
//   f4=floor((sigmoid(tx)+gx)*4)  f5=floor((sigmoid(ty)+gy)*4)
//   f6=exp(tw)*anchor_w[a2]       f7=exp(th)*anchor_h[a2]
//   f8..14: cc=(f-8)*3+a2; src anchor as=cc/7, cls k=cc%7 -> x[b, as*14+7+k, gy, gx]
// (class channels deliberately scrambled across anchors — matches the
//  reshape(B,15,A,G,G) of the concatenated feats in the reference.)
//
// R4: R3 + non-temporal on the INPUT LOADS ONLY (stores stay plain).
// R2 bundled nt loads+stores and regressed; fills sustain 7.2 TB/s with
// plain stores -> write path wants L2. Read stream has zero reuse and
// read+write working set (257MB) ~= L3 size -> nt reads free cache
// capacity for the write stream. Single-variable test vs R3.

constexpr int G   = 152;
constexpr int GG  = G * G;        // 23104, %4 == 0
constexpr int Cc  = 14;
constexpr int NTHREADS  = 256;
constexpr int TILE_ROWS = 1024;   // rows (=output 15-float groups) per block

typedef float f32x4 __attribute__((ext_vector_type(4)));

__device__ __forceinline__ float sigmoidf_(float v) {
    return 1.0f / (1.0f + __expf(-v));
}
__device__ __forceinline__ f32x4 ldg_nt(const float* p) {
    return __builtin_nontemporal_load((const f32x4*)p);
}

__global__ __launch_bounds__(NTHREADS) void decode_kernel(
    const float* __restrict__ x, const float* __restrict__ anchors,
    float* __restrict__ out, int total_rows)
{
    __shared__ f32x4 lds4[TILE_ROWS * 15 / 4];   // 3840 granules = 61440 B

    const int t  = threadIdx.x;
    const int r0 = blockIdx.x * TILE_ROWS + t * 4;   // 4 consecutive rows per thread

    if (r0 + 3 < total_rows) {
        const unsigned ba = (unsigned)r0 / (unsigned)GG;   // b*3 + a2 (same for all 4 rows)
        const int s0      = r0 - (int)ba * GG;             // %4 == 0
        const unsigned b  = ba / 3u;
        const int a2      = (int)(ba - b * 3u);
        const int gy      = s0 / G;
        const int gx0     = s0 - gy * G;                   // %4==0 -> no row wrap in the 4

        const float an_w = anchors[a2 * 2 + 0];
        const float an_h = anchors[a2 * 2 + 1];

        const float* xb = x + (size_t)(b * 42u) * GG + s0;
        const int cb = a2 * Cc;

        const f32x4 vtx = ldg_nt(xb + (size_t)(cb + 0) * GG);
        const f32x4 vty = ldg_nt(xb + (size_t)(cb + 1) * GG);
        const f32x4 vtw = ldg_nt(xb + (size_t)(cb + 2) * GG);
        const f32x4 vth = ldg_nt(xb + (size_t)(cb + 3) * GG);
        const f32x4 vim = ldg_nt(xb + (size_t)(cb + 4) * GG);
        const f32x4 vre = ldg_nt(xb + (size_t)(cb + 5) * GG);
        const f32x4 vcf = ldg_nt(xb + (size_t)(cb + 6) * GG);
        f32x4 vcls[7];
#pragma unroll
        for (int fc = 0; fc < 7; ++fc) {
            const int cc = fc * 3 + a2;
            const int as = cc / 7;
            const int k  = cc - as * 7;
            vcls[fc] = ldg_nt(xb + (size_t)(as * Cc + 7 + k) * GG);
        }

        float v[60];                                  // fully static-indexed -> VGPRs
#pragma unroll
        for (int u = 0; u < 4; ++u) {
            const float im  = vim[u];
            const float re  = vre[u];
            const float yaw = atanf(im / re);
            const float cf  = sigmoidf_(vcf[u]);
            const float ax  = floorf((sigmoidf_(vtx[u]) + (float)(gx0 + u)) * 4.0f);
            const float ay  = floorf((sigmoidf_(vty[u]) + (float)gy) * 4.0f);
            const float aw  = __expf(vtw[u]) * an_w;
            const float ah  = __expf(vth[u]) * an_h;
            v[u * 15 + 0] = im;  v[u * 15 + 1] = re;
            v[u * 15 + 2] = yaw; v[u * 15 + 3] = cf;
            v[u * 15 + 4] = ax;  v[u * 15 + 5] = ay;
            v[u * 15 + 6] = aw;  v[u * 15 + 7] = ah;
#pragma unroll
            for (int fc = 0; fc < 7; ++fc) v[u * 15 + 8 + fc] = vcls[fc][u];
        }
#pragma unroll
        for (int j = 0; j < 15; ++j) {
            f32x4 q = { v[4 * j], v[4 * j + 1], v[4 * j + 2], v[4 * j + 3] };
            lds4[15 * t + j] = q;                     // ds_write_b128, quad (7t+j)%8: conflict-free
        }
    }
    __syncthreads();

    // Coalesced float4 store of the block's 15360-float chunk (plain stores).
    const long long block_word0 = (long long)blockIdx.x * (TILE_ROWS * 15);
    const long long total_words = (long long)total_rows * 15;
    float* outp = out + block_word0;
#pragma unroll
    for (int i = 0; i < 15; ++i) {
        const int gr = i * NTHREADS + t;              // granule index within chunk
        if (block_word0 + 4 * gr + 3 < total_words) {
            f32x4 q = lds4[gr];                       // ds_read_b128, consecutive: conflict-free
            *(f32x4*)(outp + 4 * gr) = q;
        }
    }
}

extern "C" void kernel_launch(void* const* d_in, const int* in_sizes, int n_in,
                              void* d_out, int out_size, void* d_ws, size_t ws_size,
                              hipStream_t stream) {
    const float* x       = (const float*)d_in[0];
    const float* anchors = (const float*)d_in[1];
    float* out           = (float*)d_out;

    const int B          = in_sizes[0] / (3 * Cc * GG);   // 32
    const int total_rows = B * 3 * GG;                    // 2,217,984 (exact multiple of 1024)
    const int nblocks    = (total_rows + TILE_ROWS - 1) / TILE_ROWS;  // 2166

    hipLaunchKernelGGL(decode_kernel, dim3(nblocks), dim3(NTHREADS), 0, stream,
                       x, anchors, out, total_rows);
}

// Round 5
// 43.488 us; speedup vs baseline: 1.0799x; 1.0799x over previous
//
#include <hip/hip_runtime.h>

// Anchor decode (YOLO-style), B=32, A=3, C=14 (7 box/conf + 7 cls), G=152.
// out[b, a2, gy, gx, f] (flattened (B, A*G*G, 15)):
//   f0=im  f1=re  f2=atan(im/re)  f3=sigmoid(conf)
//   f4=floor((sigmoid(tx)+gx)*4)  f5=floor((sigmoid(ty)+gy)*4)
//   f6=exp(tw)*anchor_w[a2]       f7=exp(th)*anchor_h[a2]
//   f8..14: cc=(f-8)*3+a2; src anchor as=cc/7, cls k=cc%7 -> x[b, as*14+7+k, gy, gx]
// (class channels deliberately scrambled across anchors — matches the
//  reshape(B,15,A,G,G) of the concatenated feats in the reference.)
//
// R5 = revert to R3 (best: 43.69us, 5.89 TB/s = 93.6% of m13 mixed ceiling).
// Ablation history: R2 (nt loads+stores) 47.1us; R4 (nt loads only) 46.9us
// -> non-temporal LOADS cost ~7% on gfx950 streaming reads; plain loads and
// stores are the fastest cache policy for both streams. LDS b128 both phases,
// conflict-free without swizzle (write quad (7t+j)%8, read consecutive).

constexpr int G   = 152;
constexpr int GG  = G * G;        // 23104, %4 == 0
constexpr int Cc  = 14;
constexpr int NTHREADS  = 256;
constexpr int TILE_ROWS = 1024;   // rows (=output 15-float groups) per block

typedef float f32x4 __attribute__((ext_vector_type(4)));

__device__ __forceinline__ float sigmoidf_(float v) {
    return 1.0f / (1.0f + __expf(-v));
}

__global__ __launch_bounds__(NTHREADS) void decode_kernel(
    const float* __restrict__ x, const float* __restrict__ anchors,
    float* __restrict__ out, int total_rows)
{
    __shared__ f32x4 lds4[TILE_ROWS * 15 / 4];   // 3840 granules = 61440 B

    const int t  = threadIdx.x;
    const int r0 = blockIdx.x * TILE_ROWS + t * 4;   // 4 consecutive rows per thread

    if (r0 + 3 < total_rows) {
        const unsigned ba = (unsigned)r0 / (unsigned)GG;   // b*3 + a2 (same for all 4 rows)
        const int s0      = r0 - (int)ba * GG;             // %4 == 0
        const unsigned b  = ba / 3u;
        const int a2      = (int)(ba - b * 3u);
        const int gy      = s0 / G;
        const int gx0     = s0 - gy * G;                   // %4==0 -> no row wrap in the 4

        const float an_w = anchors[a2 * 2 + 0];
        const float an_h = anchors[a2 * 2 + 1];

        const float* xb = x + (size_t)(b * 42u) * GG + s0;
        const int cb = a2 * Cc;

        const f32x4 vtx = *(const f32x4*)(xb + (size_t)(cb + 0) * GG);
        const f32x4 vty = *(const f32x4*)(xb + (size_t)(cb + 1) * GG);
        const f32x4 vtw = *(const f32x4*)(xb + (size_t)(cb + 2) * GG);
        const f32x4 vth = *(const f32x4*)(xb + (size_t)(cb + 3) * GG);
        const f32x4 vim = *(const f32x4*)(xb + (size_t)(cb + 4) * GG);
        const f32x4 vre = *(const f32x4*)(xb + (size_t)(cb + 5) * GG);
        const f32x4 vcf = *(const f32x4*)(xb + (size_t)(cb + 6) * GG);
        f32x4 vcls[7];
#pragma unroll
        for (int fc = 0; fc < 7; ++fc) {
            const int cc = fc * 3 + a2;
            const int as = cc / 7;
            const int k  = cc - as * 7;
            vcls[fc] = *(const f32x4*)(xb + (size_t)(as * Cc + 7 + k) * GG);
        }

        float v[60];                                  // fully static-indexed -> VGPRs
#pragma unroll
        for (int u = 0; u < 4; ++u) {
            const float im  = vim[u];
            const float re  = vre[u];
            const float yaw = atanf(im / re);
            const float cf  = sigmoidf_(vcf[u]);
            const float ax  = floorf((sigmoidf_(vtx[u]) + (float)(gx0 + u)) * 4.0f);
            const float ay  = floorf((sigmoidf_(vty[u]) + (float)gy) * 4.0f);
            const float aw  = __expf(vtw[u]) * an_w;
            const float ah  = __expf(vth[u]) * an_h;
            v[u * 15 + 0] = im;  v[u * 15 + 1] = re;
            v[u * 15 + 2] = yaw; v[u * 15 + 3] = cf;
            v[u * 15 + 4] = ax;  v[u * 15 + 5] = ay;
            v[u * 15 + 6] = aw;  v[u * 15 + 7] = ah;
#pragma unroll
            for (int fc = 0; fc < 7; ++fc) v[u * 15 + 8 + fc] = vcls[fc][u];
        }
#pragma unroll
        for (int j = 0; j < 15; ++j) {
            f32x4 q = { v[4 * j], v[4 * j + 1], v[4 * j + 2], v[4 * j + 3] };
            lds4[15 * t + j] = q;                     // ds_write_b128, quad (7t+j)%8: conflict-free
        }
    }
    __syncthreads();

    // Coalesced float4 store of the block's 15360-float chunk (plain stores).
    const long long block_word0 = (long long)blockIdx.x * (TILE_ROWS * 15);
    const long long total_words = (long long)total_rows * 15;
    float* outp = out + block_word0;
#pragma unroll
    for (int i = 0; i < 15; ++i) {
        const int gr = i * NTHREADS + t;              // granule index within chunk
        if (block_word0 + 4 * gr + 3 < total_words) {
            f32x4 q = lds4[gr];                       // ds_read_b128, consecutive: conflict-free
            *(f32x4*)(outp + 4 * gr) = q;
        }
    }
}

extern "C" void kernel_launch(void* const* d_in, const int* in_sizes, int n_in,
                              void* d_out, int out_size, void* d_ws, size_t ws_size,
                              hipStream_t stream) {
    const float* x       = (const float*)d_in[0];
    const float* anchors = (const float*)d_in[1];
    float* out           = (float*)d_out;

    const int B          = in_sizes[0] / (3 * Cc * GG);   // 32
    const int total_rows = B * 3 * GG;                    // 2,217,984 (exact multiple of 1024)
    const int nblocks    = (total_rows + TILE_ROWS - 1) / TILE_ROWS;  // 2166

    hipLaunchKernelGGL(decode_kernel, dim3(nblocks), dim3(NTHREADS), 0, stream,
                       x, anchors, out, total_rows);
}

// Round 6
// 42.147 us; speedup vs baseline: 1.1142x; 1.0318x over previous
//
#include <hip/hip_runtime.h>

// Anchor decode (YOLO-style), B=32, A=3, C=14 (7 box/conf + 7 cls), G=152.
// out[b, a2, gy, gx, f] (flattened (B, A*G*G, 15)):
//   f0=im  f1=re  f2=atan(im/re)  f3=sigmoid(conf)
//   f4=floor((sigmoid(tx)+gx)*4)  f5=floor((sigmoid(ty)+gy)*4)
//   f6=exp(tw)*anchor_w[a2]       f7=exp(th)*anchor_h[a2]
//   f8..14: cc=(f-8)*3+a2; src anchor as=cc/7, cls k=cc%7 -> x[b, as*14+7+k, gy, gx]
//
// R6: occupancy experiment. R5 profile: OccupancyPercent 16.7 (2 blocks/CU,
// 61.4KB LDS), neither HBM stream saturated -> barrier-bubble hypothesis.
// Halve per-thread work: 2 rows/thread, TILE_ROWS=512, LDS 30,720B ->
// 5 blocks/CU = 20 waves/CU. Loads dwordx2 (8B/lane), stores dwordx4.
// History: nt hints regress (R2/R4); LDS conflicts irrelevant (R1 vs R3).

constexpr int G   = 152;
constexpr int GG  = G * G;        // 23104, even
constexpr int Cc  = 14;
constexpr int NTHREADS  = 256;
constexpr int TILE_ROWS = 512;    // rows (=output 15-float groups) per block

typedef float f32x4 __attribute__((ext_vector_type(4)));
typedef float f32x2 __attribute__((ext_vector_type(2)));

__device__ __forceinline__ float sigmoidf_(float v) {
    return 1.0f / (1.0f + __expf(-v));
}

__global__ __launch_bounds__(NTHREADS) void decode_kernel(
    const float* __restrict__ x, const float* __restrict__ anchors,
    float* __restrict__ out, int total_rows)
{
    __shared__ float lds[TILE_ROWS * 15];         // 7680 floats = 30720 B -> 5 blocks/CU

    const int t  = threadIdx.x;
    const int r0 = blockIdx.x * TILE_ROWS + t * 2;   // 2 consecutive rows per thread

    {
        const unsigned ba = (unsigned)r0 / (unsigned)GG;   // b*3 + a2 (r0 even, GG even -> no straddle)
        const int s0      = r0 - (int)ba * GG;             // even
        const unsigned b  = ba / 3u;
        const int a2      = (int)(ba - b * 3u);
        const int gy      = s0 / G;
        const int gx0     = s0 - gy * G;                   // even, G even -> gx0+1 <= 151, no row wrap

        const float an_w = anchors[a2 * 2 + 0];
        const float an_h = anchors[a2 * 2 + 1];

        const float* xb = x + (size_t)(b * 42u) * GG + s0;
        const int cb = a2 * Cc;

        const f32x2 vtx = *(const f32x2*)(xb + (size_t)(cb + 0) * GG);
        const f32x2 vty = *(const f32x2*)(xb + (size_t)(cb + 1) * GG);
        const f32x2 vtw = *(const f32x2*)(xb + (size_t)(cb + 2) * GG);
        const f32x2 vth = *(const f32x2*)(xb + (size_t)(cb + 3) * GG);
        const f32x2 vim = *(const f32x2*)(xb + (size_t)(cb + 4) * GG);
        const f32x2 vre = *(const f32x2*)(xb + (size_t)(cb + 5) * GG);
        const f32x2 vcf = *(const f32x2*)(xb + (size_t)(cb + 6) * GG);
        f32x2 vcls[7];
#pragma unroll
        for (int fc = 0; fc < 7; ++fc) {
            const int cc = fc * 3 + a2;
            const int as = cc / 7;
            const int k  = cc - as * 7;
            vcls[fc] = *(const f32x2*)(xb + (size_t)(as * Cc + 7 + k) * GG);
        }

        float v[30];                                  // fully static-indexed -> VGPRs
#pragma unroll
        for (int u = 0; u < 2; ++u) {
            const float im  = vim[u];
            const float re  = vre[u];
            const float yaw = atanf(im / re);
            const float cf  = sigmoidf_(vcf[u]);
            const float ax  = floorf((sigmoidf_(vtx[u]) + (float)(gx0 + u)) * 4.0f);
            const float ay  = floorf((sigmoidf_(vty[u]) + (float)gy) * 4.0f);
            const float aw  = __expf(vtw[u]) * an_w;
            const float ah  = __expf(vth[u]) * an_h;
            v[u * 15 + 0] = im;  v[u * 15 + 1] = re;
            v[u * 15 + 2] = yaw; v[u * 15 + 3] = cf;
            v[u * 15 + 4] = ax;  v[u * 15 + 5] = ay;
            v[u * 15 + 6] = aw;  v[u * 15 + 7] = ah;
#pragma unroll
            for (int fc = 0; fc < 7; ++fc) v[u * 15 + 8 + fc] = vcls[fc][u];
        }
        // 15 x ds_write_b64; word offset 30t+2j even, bank-pair spread = baseline
#pragma unroll
        for (int j = 0; j < 15; ++j) {
            f32x2 q = { v[2 * j], v[2 * j + 1] };
            *(f32x2*)&lds[30 * t + 2 * j] = q;
        }
    }
    __syncthreads();

    // Coalesced float4 store of the block's 7680-float chunk.
    // 1920 x4-granules, 256 threads -> 7 full rounds + half round (EXEC-masked).
    float* outp = out + (long long)blockIdx.x * (TILE_ROWS * 15);
#pragma unroll
    for (int i = 0; i < 8; ++i) {
        const int gr = i * NTHREADS + t;
        if (gr < TILE_ROWS * 15 / 4) {
            f32x4 q = *(const f32x4*)&lds[4 * gr];    // ds_read_b128, consecutive: baseline
            *(f32x4*)(outp + 4 * gr) = q;
        }
    }
}

extern "C" void kernel_launch(void* const* d_in, const int* in_sizes, int n_in,
                              void* d_out, int out_size, void* d_ws, size_t ws_size,
                              hipStream_t stream) {
    const float* x       = (const float*)d_in[0];
    const float* anchors = (const float*)d_in[1];
    float* out           = (float*)d_out;

    const int B          = in_sizes[0] / (3 * Cc * GG);   // 32
    const int total_rows = B * 3 * GG;                    // 2,217,984 = 512 * 4332 exactly
    const int nblocks    = total_rows / TILE_ROWS;        // 4332

    hipLaunchKernelGGL(decode_kernel, dim3(nblocks), dim3(NTHREADS), 0, stream,
                       x, anchors, out, total_rows);
}

// Round 7
// 42.063 us; speedup vs baseline: 1.1164x; 1.0020x over previous
//
#include <hip/hip_runtime.h>

// Anchor decode (YOLO-style), B=32, A=3, C=14 (7 box/conf + 7 cls), G=152.
// out[b, a2, gy, gx, f] (flattened (B, A*G*G, 15)):
//   f0=im  f1=re  f2=atan(im/re)  f3=sigmoid(conf)
//   f4=floor((sigmoid(tx)+gx)*4)  f5=floor((sigmoid(ty)+gy)*4)
//   f6=exp(tw)*anchor_w[a2]       f7=exp(th)*anchor_h[a2]
//   f8..14: cc=(f-8)*3+a2; src anchor as=cc/7, cls k=cc%7 -> x[b, as*14+7+k, gy, gx]
//
// R7: wave-autonomous tiles. Each wave owns 64 rows (GG=23104=361*64 ->
// never straddles a (b,a2) boundary): 1 row/lane, 14 coalesced dword loads,
// 15 LDS writes at 15*lane (gcd(15,32)=1, conflict-free), wave-local
// readback of 240 consecutive float4 granules -> coalesced 1KB stores.
// NO __syncthreads (intra-wave LDS dep, auto lgkmcnt + wave_barrier fence).
// LDS 15360B/block + __launch_bounds__(256,8) -> 8 blocks/CU, 32 waves/CU
// (100% occupancy), every wave free-running.
// History: nt hints regress (R2/R4); LDS conflicts irrelevant (R1/R3);
// occupancy 2->5 blocks/CU gave -1.3us (R6).

constexpr int G   = 152;
constexpr int GG  = G * G;        // 23104 = 361*64
constexpr int Cc  = 14;
constexpr int NTHREADS = 256;     // 4 waves/block, 64 rows per wave

typedef float f32x4 __attribute__((ext_vector_type(4)));

__device__ __forceinline__ float sigmoidf_(float v) {
    return 1.0f / (1.0f + __expf(-v));
}

__global__ __launch_bounds__(NTHREADS, 8) void decode_kernel(
    const float* __restrict__ x, const float* __restrict__ anchors,
    float* __restrict__ out)
{
    __shared__ f32x4 lds4[NTHREADS * 15 / 4];     // 960 granules = 15360 B
    float* ldsf = (float*)lds4;

    const int t = threadIdx.x;
    const int w = t >> 6;                         // wave id in block
    const int l = t & 63;                         // lane
    const int r = blockIdx.x * NTHREADS + t;      // one row per lane; grid exact

    const unsigned ba = (unsigned)r / (unsigned)GG;    // b*3 + a2 (uniform per wave)
    const int s       = r - (int)ba * GG;
    const unsigned b  = ba / 3u;
    const int a2      = (int)(ba - b * 3u);
    const int gy      = s / G;
    const int gx      = s - gy * G;

    const float an_w = anchors[a2 * 2 + 0];
    const float an_h = anchors[a2 * 2 + 1];

    const float* xb = x + (size_t)(b * 42u) * GG + s;
    const int cb = a2 * Cc;

    const float tx = xb[(size_t)(cb + 0) * GG];
    const float ty = xb[(size_t)(cb + 1) * GG];
    const float tw = xb[(size_t)(cb + 2) * GG];
    const float th = xb[(size_t)(cb + 3) * GG];
    const float im = xb[(size_t)(cb + 4) * GG];
    const float re = xb[(size_t)(cb + 5) * GG];
    const float cf = xb[(size_t)(cb + 6) * GG];
    float cls[7];
#pragma unroll
    for (int fc = 0; fc < 7; ++fc) {
        const int cc = fc * 3 + a2;
        const int as = cc / 7;
        const int k  = cc - as * 7;
        cls[fc] = xb[(size_t)(as * Cc + 7 + k) * GG];
    }

    float* wb = ldsf + 15 * t;                    // word 15t+j: bank gcd(15,32)=1 -> conflict-free
    wb[0] = im;
    wb[1] = re;
    wb[2] = atanf(im / re);
    wb[3] = sigmoidf_(cf);
    wb[4] = floorf((sigmoidf_(tx) + (float)gx) * 4.0f);
    wb[5] = floorf((sigmoidf_(ty) + (float)gy) * 4.0f);
    wb[6] = __expf(tw) * an_w;
    wb[7] = __expf(th) * an_h;
#pragma unroll
    for (int fc = 0; fc < 7; ++fc) wb[8 + fc] = cls[fc];

    __builtin_amdgcn_wave_barrier();              // scheduling fence only; lgkmcnt auto-inserted

    // Wave-local readback + coalesced stores: wave covers granules [240w, 240w+240).
    float* outp = out + (long long)blockIdx.x * (NTHREADS * 15);
#pragma unroll
    for (int i = 0; i < 4; ++i) {
        const int idx = 64 * i + l;
        if (idx < 240) {                          // last round: lanes 48..63 masked
            const int gr = 240 * w + idx;
            f32x4 q = lds4[gr];                   // consecutive b128: conflict-free
            *(f32x4*)(outp + 4 * gr) = q;
        }
    }
}

extern "C" void kernel_launch(void* const* d_in, const int* in_sizes, int n_in,
                              void* d_out, int out_size, void* d_ws, size_t ws_size,
                              hipStream_t stream) {
    const float* x       = (const float*)d_in[0];
    const float* anchors = (const float*)d_in[1];
    float* out           = (float*)d_out;

    const int B          = in_sizes[0] / (3 * Cc * GG);   // 32
    const int total_rows = B * 3 * GG;                    // 2,217,984 = 256 * 8664 exactly
    const int nblocks    = total_rows / NTHREADS;         // 8664

    hipLaunchKernelGGL(decode_kernel, dim3(nblocks), dim3(NTHREADS), 0, stream,
                       x, anchors, out);
}